// Round 11
// baseline (356.656 us; speedup 1.0000x reference)
//
#include <hip/hip_runtime.h>

// ---------------------------------------------------------------------------
// PAM: out = gamma * softmax((X Wb)(X Wc)^T) (X Wd) + X
// B=4, N=4096, C=512, CR=64. fp32 in/out; bf16 MFMA with hi/lo Q/K split.
// Materialized-P design: P = exp(S - 90) bf16 (softmax shift-invariance).
// Round 19: pv prefetch depth 1 -> 2. R18 (correct counted-vmcnt + XCD
// swizzle) cut FETCH 287->98 MB and got 83.4us, but step time ~3100cyc vs
// ~500cyc compute => effective load latency L~2600cyc (L3/fabric queuing).
// d=1 recurrence T = C + max(0, L-T) pins T~L. Now 3 buffers (96KB, 1
// block/CU), stage(t+2), vmcnt(16) at the wait (24 outstanding -> retires
// exactly tile t; t+1/t+2 stay in flight). T = C + max(0, L-2T) -> ~1030cyc.
// Loop unrolled x3 (static buffer indices, rule #20). Tail vmcnt(8)/(0).
// Stage/compute bodies, XOR swizzle, XCD mapping identical to R18.
// ---------------------------------------------------------------------------

typedef __bf16 bf16_t;
typedef __bf16 bf16x8 __attribute__((ext_vector_type(8)));
typedef float f32x4 __attribute__((ext_vector_type(4)));
typedef unsigned long long u64;

#define NN 4096
#define CC 512
#define VSTRIDE 4160u
#define PSTRIDE 4160u
#define ESHIFT 90.0f

// workspace layout, bf16 elements. P overlaps the W and Xfrag regions
// (both dead after qkv).
#define OFF_QH 0u
#define OFF_QL 1048576u
#define OFF_KH 2097152u
#define OFF_KL 3145728u
#define OFF_VT 4194304u            // Vt[b][c][VSTRIDE]
#define OFF_WBH 29491200u          // Wb hi, frag-major [4][16][64][8]
#define OFF_WBL 29523968u
#define OFF_WCH 29556736u
#define OFF_WCL 29589504u
#define OFF_WD  29622272u          // Wd, frag-major [8][4][16][64][8]
#define OFF_XHF 46137344u          // X hi, frag-major [256][4][16][64][8]
#define OFF_XLF 54525952u          // X lo
#define OFF_P   12713984u          // P[b][n][PSTRIDE] bf16 (136 MB)
#define PBATCH  17039360u          // 4096*4160

static __device__ __forceinline__ f32x4 mfma16(bf16x8 a, bf16x8 b, f32x4 c) {
    return __builtin_amdgcn_mfma_f32_16x16x32_bf16(a, b, c, 0, 0, 0);
}

static __device__ __forceinline__ void load_lds16(const bf16_t* g, bf16_t* l) {
    __builtin_amdgcn_global_load_lds(
        (const __attribute__((address_space(1))) unsigned int*)g,
        (__attribute__((address_space(3))) unsigned int*)l, 16, 0, 0);
}

// ------------------- K0: prep (W -> fragment-major hi/lo) -------------------
__global__ __launch_bounds__(256) void prep_kernel(const float* __restrict__ Wb,
                                                   const float* __restrict__ Wc,
                                                   const float* __restrict__ Wd,
                                                   bf16_t* __restrict__ ws) {
    int j = blockIdx.x * 256 + threadIdx.x;
    if (j < 8192) {                            // Wb / Wc hi+lo frags
        const float* W = (j < 4096) ? Wb : Wc;
        unsigned oh = (j < 4096) ? OFF_WBH : OFF_WCH;
        unsigned ol = (j < 4096) ? OFF_WBL : OFF_WCL;
        int jc = j & 4095;
        int nt = jc >> 10, ks = (jc >> 6) & 15, lane = jc & 63;
        int quad = lane >> 4, l16 = lane & 15;
        int col = nt * 16 + l16, k0 = ks * 32 + quad * 8;
        bf16x8 h, l;
#pragma unroll
        for (int i = 0; i < 8; ++i) {
            float v = W[(k0 + i) * 64 + col];
            bf16_t hv = (bf16_t)v;
            h[i] = hv;
            l[i] = (bf16_t)(v - (float)hv);
        }
        *(bf16x8*)(ws + oh + (size_t)jc * 8) = h;
        *(bf16x8*)(ws + ol + (size_t)jc * 8) = l;
    } else if (j < 40960) {                    // Wd frags (hi only)
        int jc = j - 8192;
        int nT = jc >> 12, nt = (jc >> 10) & 3, ks = (jc >> 6) & 15, lane = jc & 63;
        int quad = lane >> 4, l16 = lane & 15;
        int col = nT * 64 + nt * 16 + l16, k0 = ks * 32 + quad * 8;
        bf16x8 h;
#pragma unroll
        for (int i = 0; i < 8; ++i)
            h[i] = (bf16_t)Wd[(k0 + i) * 512 + col];
        *(bf16x8*)(ws + OFF_WD + (size_t)jc * 8) = h;
    }
}

// ------------------- K0b: xprep (X -> fragment-major hi/lo bf16) ------------
__global__ __launch_bounds__(256) void xprep_kernel(const float* __restrict__ x,
                                                    bf16_t* __restrict__ ws) {
    int mt = blockIdx.x;
    int tid = threadIdx.x;
    const float* xb = x + (size_t)mt * 32768;
#pragma unroll
    for (int it = 0; it < 16; ++it) {
        int c = it * 256 + tid;                // 16B-pair chunk: 8 f32
        int row = c >> 6, col8 = c & 63;
        f32x4 a0 = *(const f32x4*)(xb + c * 8);
        f32x4 a1 = *(const f32x4*)(xb + c * 8 + 4);
        bf16x8 h, l;
#pragma unroll
        for (int jj = 0; jj < 4; ++jj) {
            bf16_t h0 = (bf16_t)a0[jj];
            bf16_t h1 = (bf16_t)a1[jj];
            h[jj] = h0;     l[jj] = (bf16_t)(a0[jj] - (float)h0);
            h[4 + jj] = h1; l[4 + jj] = (bf16_t)(a1[jj] - (float)h1);
        }
        int w = row >> 4, l16 = row & 15, ks = col8 >> 2, quad = col8 & 3;
        size_t dst = (size_t)mt * 32768 + w * 8192 + ks * 512 + (quad * 16 + l16) * 8;
        *(bf16x8*)(ws + OFF_XHF + dst) = h;
        *(bf16x8*)(ws + OFF_XLF + dst) = l;
    }
}

// --------------------------- K1: fused QKV projection -----------------------
// grid (256, 6): blockIdx.x = 64-row stripe, blockIdx.y = output group.
// All operand loads are fragment-major: base + lane*16B, fully coalesced.
__global__ __launch_bounds__(256, 1) void qkv_kernel(bf16_t* __restrict__ ws) {
    int mt = blockIdx.x;                       // 0..255
    int g  = blockIdx.y;                       // 0..5
    int tid = threadIdx.x;
    int w = tid >> 6, lane = tid & 63, quad = lane >> 4, l16 = lane & 15;

    __shared__ __align__(16) bf16_t Vs[64][72];

    size_t xoff = (size_t)mt * 32768 + w * 8192 + lane * 8;

    if (g < 2) {
        bf16x8 xh[16], xl[16];
#pragma unroll
        for (int ks = 0; ks < 16; ++ks)
            xh[ks] = *(const bf16x8*)(ws + OFF_XHF + xoff + ks * 512);
#pragma unroll
        for (int ks = 0; ks < 16; ++ks)
            xl[ks] = *(const bf16x8*)(ws + OFF_XLF + xoff + ks * 512);

        const bf16_t* whf = ws + (g == 0 ? OFF_WBH : OFF_WCH) + lane * 8;
        const bf16_t* wlf = ws + (g == 0 ? OFF_WBL : OFF_WCL) + lane * 8;
        f32x4 acc[4];
#pragma unroll
        for (int nt = 0; nt < 4; ++nt) acc[nt] = (f32x4){0.f, 0.f, 0.f, 0.f};
#pragma unroll
        for (int ks = 0; ks < 16; ++ks) {
#pragma unroll
            for (int nt = 0; nt < 4; ++nt) {
                bf16x8 bh = *(const bf16x8*)(whf + (nt * 16 + ks) * 512);
                bf16x8 bl = *(const bf16x8*)(wlf + (nt * 16 + ks) * 512);
                acc[nt] = mfma16(xh[ks], bh, acc[nt]);
                acc[nt] = mfma16(xh[ks], bl, acc[nt]);
                acc[nt] = mfma16(xl[ks], bh, acc[nt]);
            }
        }
        unsigned base_h = (g == 0) ? OFF_QH : OFF_KH;
        unsigned base_l = (g == 0) ? OFF_QL : OFF_KL;
#pragma unroll
        for (int nt = 0; nt < 4; ++nt) {
            int gc = nt * 16 + l16;
#pragma unroll
            for (int r = 0; r < 4; ++r) {
                int gr = mt * 64 + w * 16 + quad * 4 + r;
                int b = gr >> 12, np = gr & 4095;
                float v = acc[nt][r];
                bf16_t h = (bf16_t)v;
                size_t o = ((size_t)(b * 4096 + np)) * 64 + gc;
                ws[base_h + o] = h;
                ws[base_l + o] = (bf16_t)(v - (float)h);
            }
        }
    } else {
        bf16x8 xh[16];
#pragma unroll
        for (int ks = 0; ks < 16; ++ks)
            xh[ks] = *(const bf16x8*)(ws + OFF_XHF + xoff + ks * 512);

        for (int t = 0; t < 2; ++t) {
            int nT = (g - 2) * 2 + t;
            const bf16_t* wdf = ws + OFF_WD + lane * 8;
            f32x4 acc[4];
#pragma unroll
            for (int nt = 0; nt < 4; ++nt) acc[nt] = (f32x4){0.f, 0.f, 0.f, 0.f};
#pragma unroll
            for (int ks = 0; ks < 16; ++ks) {
#pragma unroll
                for (int nt = 0; nt < 4; ++nt) {
                    bf16x8 bb = *(const bf16x8*)(wdf + (size_t)(((nT * 4 + nt) * 16 + ks)) * 512);
                    acc[nt] = mfma16(xh[ks], bb, acc[nt]);
                }
            }
#pragma unroll
            for (int nt = 0; nt < 4; ++nt) {
                bf16_t pk[4];
#pragma unroll
                for (int r = 0; r < 4; ++r) pk[r] = (bf16_t)acc[nt][r];
                *(u64*)&Vs[nt * 16 + l16][w * 16 + quad * 4] = *(u64*)pk;
            }
            __syncthreads();
            int gr0 = mt * 64;
            int bb = gr0 >> 12, np0 = gr0 & 4095;
            int ch = tid >> 2, seg = tid & 3;
            f32x4 d0 = *(const f32x4*)&Vs[ch][seg * 16];
            f32x4 d1 = *(const f32x4*)&Vs[ch][seg * 16 + 8];
            bf16_t* dst = ws + OFF_VT +
                ((size_t)bb * 512 + (size_t)(nT * 64 + ch)) * VSTRIDE + np0 + seg * 16;
            *(f32x4*)(dst) = d0;
            *(f32x4*)(dst + 8) = d1;
            __syncthreads();
        }
    }
}

// --------------------------- K2: scores + exp -------------------------------
__global__ __launch_bounds__(256, 2) void score_kernel(bf16_t* __restrict__ ws) {
    int idx = blockIdx.x;
    int mt = idx & 31;
    int nt = (idx >> 5) & 31;
    int b  = idx >> 10;
    int tid = threadIdx.x;
    int w = tid >> 6, lane = tid & 63, quad = lane >> 4, l16 = lane & 15;
    int wr = w >> 1, wc = w & 1;

    __shared__ __align__(16) bf16_t Ls[128][136];

    const bf16_t* Qh = ws + OFF_QH + (size_t)b * NN * 64;
    const bf16_t* Ql = ws + OFF_QL + (size_t)b * NN * 64;
    const bf16_t* Kh = ws + OFF_KH + (size_t)b * NN * 64;
    const bf16_t* Kl = ws + OFF_KL + (size_t)b * NN * 64;

    bf16x8 qh[4][2], ql[4][2];
#pragma unroll
    for (int rt = 0; rt < 4; ++rt) {
        size_t qo = (size_t)(nt * 128 + wr * 64 + rt * 16 + l16) * 64 + quad * 8;
        qh[rt][0] = *(const bf16x8*)(Qh + qo);
        qh[rt][1] = *(const bf16x8*)(Qh + qo + 32);
        ql[rt][0] = *(const bf16x8*)(Ql + qo);
        ql[rt][1] = *(const bf16x8*)(Ql + qo + 32);
    }

    f32x4 s[4][4];
#pragma unroll
    for (int ct = 0; ct < 4; ++ct) {
        size_t ko = (size_t)(mt * 128 + wc * 64 + ct * 16 + l16) * 64 + quad * 8;
        bf16x8 kh0 = *(const bf16x8*)(Kh + ko);
        bf16x8 kh1 = *(const bf16x8*)(Kh + ko + 32);
        bf16x8 kl0 = *(const bf16x8*)(Kl + ko);
        bf16x8 kl1 = *(const bf16x8*)(Kl + ko + 32);
#pragma unroll
        for (int rt = 0; rt < 4; ++rt) {
            f32x4 a = (f32x4){0.f, 0.f, 0.f, 0.f};
            a = mfma16(qh[rt][0], kh0, a);
            a = mfma16(qh[rt][1], kh1, a);
            a = mfma16(qh[rt][0], kl0, a);
            a = mfma16(qh[rt][1], kl1, a);
            a = mfma16(ql[rt][0], kh0, a);
            a = mfma16(ql[rt][1], kh1, a);
            s[rt][ct] = a;
        }
    }

#pragma unroll
    for (int rt = 0; rt < 4; ++rt)
#pragma unroll
        for (int ct = 0; ct < 4; ++ct)
#pragma unroll
            for (int r = 0; r < 4; ++r) {
                float p = __expf(s[rt][ct][r] - ESHIFT);
                Ls[wr * 64 + rt * 16 + quad * 4 + r][wc * 64 + ct * 16 + l16] = (bf16_t)p;
            }
    __syncthreads();

    bf16_t* P = ws + OFF_P + (size_t)b * PBATCH;
    int row0 = tid >> 4, chunk = tid & 15;
#pragma unroll
    for (int it = 0; it < 8; ++it) {
        int row = it * 16 + row0;
        f32x4 d = *(const f32x4*)&Ls[row][chunk * 8];
        *(f32x4*)(P + (size_t)(nt * 128 + row) * PSTRIDE + mt * 128 + chunk * 8) = d;
    }
}

// --------------------------- K3: O = P V + epilogue -------------------------
// Block = XCD-swizzled (b, nt, ct4): 128x128 output, K=4096 in 64 steps of
// 64. THREE LDS buffers (96 KB, 1 block/CU), prefetch distance 2:
//   s_barrier; stage(t+2); vmcnt(16); s_barrier; sched_barrier; compute(t).
// At the wait the FIFO holds tiles t,t+1,t+2 (24 loads) -> vmcnt(16) retires
// exactly tile t; t+1/t+2 cross the barrier in flight. barrier_A frees
// buf((t+2)%3) = buf((t-1)%3) (compute(t-1) done; lgkmcnt waits before its
// MFMAs drain the ds_reads pre-barrier). Unrolled x3 -> static buffer
// indices (rule #20). Tail: vmcnt(8)->compute(62), vmcnt(0)->compute(63).
// XOR chunk swizzle (tid&7)^(row&7) both-sides. osum static.
__global__ __launch_bounds__(256, 2) void pv_kernel(const float* __restrict__ x,
                                                    const float* __restrict__ gamma_p,
                                                    const bf16_t* __restrict__ ws,
                                                    float* __restrict__ out) {
    int i = blockIdx.x;
    // XCD swizzle: siblings {ct4=0..3 of one (b,nt)} share i&7 -> same XCD.
    int xcd = i & 7, r = i >> 3;
    int ct4 = r & 3, gu = r >> 2;
    int g = gu * 8 + xcd;                      // 0..127
    int b = g & 3, nt = g >> 2;                // nt 0..31
    int tid = threadIdx.x;
    int w = tid >> 6, lane = tid & 63, quad = lane >> 4, l16 = lane & 15;
    int wr = w >> 1, wc = w & 1;

    __shared__ __align__(16) bf16_t PtA[3 * 8192];   // 3 x [128 rows][64 m]
    __shared__ __align__(16) bf16_t VtA[3 * 8192];   // 3 x [128 ch][64 m]

    const bf16_t* P = ws + OFF_P + (size_t)b * PBATCH + (size_t)(nt * 128) * PSTRIDE;
    const bf16_t* V = ws + OFF_VT + (size_t)b * CC * VSTRIDE + (size_t)(ct4 * 128) * VSTRIDE;

    // Staging: thread tid -> row sr = tid>>3 (0..31, +32/64/96), dest chunk
    // tid&7; source chunk pre-swizzled sc = (tid&7) ^ (sr&7).
    int sr = tid >> 3;
    int sc = (tid & 7) ^ (sr & 7);
    const bf16_t* gp = P + (size_t)sr * PSTRIDE + sc * 8;
    const bf16_t* gv = V + (size_t)sr * VSTRIDE + sc * 8;

    f32x4 o[4][4];
#pragma unroll
    for (int rt = 0; rt < 4; ++rt)
#pragma unroll
        for (int ct = 0; ct < 4; ++ct) o[rt][ct] = (f32x4){0.f, 0.f, 0.f, 0.f};
    f32x4 osum[4];
#pragma unroll
    for (int rt = 0; rt < 4; ++rt) osum[rt] = (f32x4){0.f, 0.f, 0.f, 0.f};

    bf16_t onev = (bf16_t)1.0f;
    bf16x8 vones = {onev, onev, onev, onev, onev, onev, onev, onev};

    auto stage = [&](int buf, int t) {
        int m0 = t * 64;
        bf16_t* pd = PtA + buf * 8192;
        bf16_t* vd = VtA + buf * 8192;
        load_lds16(gp + m0,                  pd + tid * 8);
        load_lds16(gp + 32u * PSTRIDE + m0,  pd + 2048 + tid * 8);
        load_lds16(gp + 64u * PSTRIDE + m0,  pd + 4096 + tid * 8);
        load_lds16(gp + 96u * PSTRIDE + m0,  pd + 6144 + tid * 8);
        load_lds16(gv + m0,                  vd + tid * 8);
        load_lds16(gv + 32u * VSTRIDE + m0,  vd + 2048 + tid * 8);
        load_lds16(gv + 64u * VSTRIDE + m0,  vd + 4096 + tid * 8);
        load_lds16(gv + 96u * VSTRIDE + m0,  vd + 6144 + tid * 8);
    };

    auto compute = [&](int buf) {
        const bf16_t* pb = PtA + buf * 8192;
        const bf16_t* vbuf = VtA + buf * 8192;
#pragma unroll
        for (int kk = 0; kk < 2; ++kk) {
            bf16x8 pa[4], vb[4];
#pragma unroll
            for (int rt = 0; rt < 4; ++rt) {
                int R = wr * 64 + rt * 16 + l16;
                int mc = (kk * 4 + quad) ^ (R & 7);
                pa[rt] = *(const bf16x8*)(pb + R * 64 + mc * 8);
            }
#pragma unroll
            for (int ct = 0; ct < 4; ++ct) {
                int Rv = wc * 64 + ct * 16 + l16;
                int mc = (kk * 4 + quad) ^ (Rv & 7);
                vb[ct] = *(const bf16x8*)(vbuf + Rv * 64 + mc * 8);
            }
#pragma unroll
            for (int ct = 0; ct < 4; ++ct)
#pragma unroll
                for (int rt = 0; rt < 4; ++rt)
                    o[rt][ct] = mfma16(pa[rt], vb[ct], o[rt][ct]);
            if (wc == 0) {
                osum[0] = mfma16(pa[0], vones, osum[0]);
                osum[1] = mfma16(pa[1], vones, osum[1]);
                osum[2] = mfma16(pa[2], vones, osum[2]);
                osum[3] = mfma16(pa[3], vones, osum[3]);
            }
        }
    };

#define PV_STEP(bufA, bufS, tnext)                            \
    __builtin_amdgcn_s_barrier();                             \
    stage(bufS, tnext);                                       \
    asm volatile("s_waitcnt vmcnt(16)" ::: "memory");         \
    __builtin_amdgcn_s_barrier();                             \
    __builtin_amdgcn_sched_barrier(0);                        \
    compute(bufA);

    // prologue: tiles 0,1 in flight
    stage(0, 0);
    stage(1, 1);

    // steps t=0..59 (20 x 3), staging tiles 2..61
    for (int tt = 0; tt < 60; tt += 3) {
        PV_STEP(0, 2, tt + 2)                  // compute t=tt   (buf0)
        PV_STEP(1, 0, tt + 3)                  // compute t=tt+1 (buf1)
        PV_STEP(2, 1, tt + 4)                  // compute t=tt+2 (buf2)
    }
    // t=60 (buf0), stage tile 62 -> buf2
    PV_STEP(0, 2, 62)
    // t=61 (buf1), stage tile 63 -> buf0
    PV_STEP(1, 0, 63)
    // t=62 (buf2): outstanding 62,63 = 16 -> vmcnt(8) retires 62
    __builtin_amdgcn_s_barrier();
    asm volatile("s_waitcnt vmcnt(8)" ::: "memory");
    __builtin_amdgcn_s_barrier();
    __builtin_amdgcn_sched_barrier(0);
    compute(2);
    // t=63 (buf0): vmcnt(0) retires 63
    asm volatile("s_waitcnt vmcnt(0)" ::: "memory");
    __builtin_amdgcn_s_barrier();
    __builtin_amdgcn_sched_barrier(0);
    compute(0);
#undef PV_STEP

    // rsum via LDS: PtA buf1 region is dead (last read at t=61; all waves
    // passed the t=62/63 barriers). Final compute reads buf0 only -> no
    // overlap with the 512 B used here.
    float* rsum_s = (float*)&PtA[8192];
    if (wc == 0 && l16 == 0) {
#pragma unroll
        for (int rt = 0; rt < 4; ++rt)
#pragma unroll
            for (int rr = 0; rr < 4; ++rr)
                rsum_s[wr * 64 + rt * 16 + quad * 4 + rr] = osum[rt][rr];
    }
    __syncthreads();

    float gmm = gamma_p[0];
#pragma unroll
    for (int rt = 0; rt < 4; ++rt) {
        f32x4 rs = *(const f32x4*)&rsum_s[wr * 64 + rt * 16 + quad * 4];
        f32x4 linv;
#pragma unroll
        for (int rr = 0; rr < 4; ++rr) linv[rr] = 1.0f / rs[rr];
#pragma unroll
        for (int ct = 0; ct < 4; ++ct) {
#pragma unroll
            for (int rr = 0; rr < 4; ++rr) {
                int n = nt * 128 + wr * 64 + rt * 16 + quad * 4 + rr;
                int c = ct4 * 128 + wc * 64 + ct * 16 + l16;
                size_t off = ((size_t)(b * 4096 + n)) * 512 + c;
                out[off] = gmm * (o[rt][ct][rr] * linv[rr]) + x[off];
            }
        }
    }
}

// ---------------------------------------------------------------------------
extern "C" void kernel_launch(void* const* d_in, const int* in_sizes, int n_in,
                              void* d_out, int out_size, void* d_ws, size_t ws_size,
                              hipStream_t stream) {
    const float* x     = (const float*)d_in[0];
    const float* Wb    = (const float*)d_in[1];
    const float* Wc    = (const float*)d_in[2];
    const float* Wd    = (const float*)d_in[3];
    const float* gamma = (const float*)d_in[4];
    bf16_t* ws = (bf16_t*)d_ws;
    float* out = (float*)d_out;

    prep_kernel<<<160, 256, 0, stream>>>(Wb, Wc, Wd, ws);
    xprep_kernel<<<256, 256, 0, stream>>>(x, ws);
    qkv_kernel<<<dim3(256, 6), 256, 0, stream>>>(ws);
    score_kernel<<<4096, 256, 0, stream>>>(ws);
    pv_kernel<<<512, 256, 0, stream>>>(x, gamma, ws, out);
}

// Round 12
// 292.392 us; speedup vs baseline: 1.2198x; 1.2198x over previous
//
#include <hip/hip_runtime.h>

// ---------------------------------------------------------------------------
// PAM: out = gamma * softmax((X Wb)(X Wc)^T) (X Wd) + X
// B=4, N=4096, C=512, CR=64. fp32 in/out; bf16 MFMA with hi/lo Q/K split.
// Materialized-P design: P = exp(S - 90) bf16 (softmax shift-invariance).
// Round 20: (1) pv reverted to the exact R18 form (83.4us proven: K-step 64,
// 2 buffers / 64KB -> 2 blocks/CU, counted vmcnt(8) 2-barrier step, XCD
// swizzle; R19's depth-2/96KB dropped to 1 block/CU and LOST the inter-block
// overlap -> 146us). (2) score_kernel gets T1 XCD chunking (m204 bijective,
// orig=(i&7)*512+(i>>3)): each XCD runs 16 complete (b,nt) groups, so the
// Q-tile and the whole K[b] set (~2MB) stay L2-resident per XCD.
// ---------------------------------------------------------------------------

typedef __bf16 bf16_t;
typedef __bf16 bf16x8 __attribute__((ext_vector_type(8)));
typedef float f32x4 __attribute__((ext_vector_type(4)));
typedef unsigned long long u64;

#define NN 4096
#define CC 512
#define VSTRIDE 4160u
#define PSTRIDE 4160u
#define ESHIFT 90.0f

// workspace layout, bf16 elements. P overlaps the W and Xfrag regions
// (both dead after qkv).
#define OFF_QH 0u
#define OFF_QL 1048576u
#define OFF_KH 2097152u
#define OFF_KL 3145728u
#define OFF_VT 4194304u            // Vt[b][c][VSTRIDE]
#define OFF_WBH 29491200u          // Wb hi, frag-major [4][16][64][8]
#define OFF_WBL 29523968u
#define OFF_WCH 29556736u
#define OFF_WCL 29589504u
#define OFF_WD  29622272u          // Wd, frag-major [8][4][16][64][8]
#define OFF_XHF 46137344u          // X hi, frag-major [256][4][16][64][8]
#define OFF_XLF 54525952u          // X lo
#define OFF_P   12713984u          // P[b][n][PSTRIDE] bf16 (136 MB)
#define PBATCH  17039360u          // 4096*4160

static __device__ __forceinline__ f32x4 mfma16(bf16x8 a, bf16x8 b, f32x4 c) {
    return __builtin_amdgcn_mfma_f32_16x16x32_bf16(a, b, c, 0, 0, 0);
}

static __device__ __forceinline__ void load_lds16(const bf16_t* g, bf16_t* l) {
    __builtin_amdgcn_global_load_lds(
        (const __attribute__((address_space(1))) unsigned int*)g,
        (__attribute__((address_space(3))) unsigned int*)l, 16, 0, 0);
}

// ------------------- K0: prep (W -> fragment-major hi/lo) -------------------
__global__ __launch_bounds__(256) void prep_kernel(const float* __restrict__ Wb,
                                                   const float* __restrict__ Wc,
                                                   const float* __restrict__ Wd,
                                                   bf16_t* __restrict__ ws) {
    int j = blockIdx.x * 256 + threadIdx.x;
    if (j < 8192) {                            // Wb / Wc hi+lo frags
        const float* W = (j < 4096) ? Wb : Wc;
        unsigned oh = (j < 4096) ? OFF_WBH : OFF_WCH;
        unsigned ol = (j < 4096) ? OFF_WBL : OFF_WCL;
        int jc = j & 4095;
        int nt = jc >> 10, ks = (jc >> 6) & 15, lane = jc & 63;
        int quad = lane >> 4, l16 = lane & 15;
        int col = nt * 16 + l16, k0 = ks * 32 + quad * 8;
        bf16x8 h, l;
#pragma unroll
        for (int i = 0; i < 8; ++i) {
            float v = W[(k0 + i) * 64 + col];
            bf16_t hv = (bf16_t)v;
            h[i] = hv;
            l[i] = (bf16_t)(v - (float)hv);
        }
        *(bf16x8*)(ws + oh + (size_t)jc * 8) = h;
        *(bf16x8*)(ws + ol + (size_t)jc * 8) = l;
    } else if (j < 40960) {                    // Wd frags (hi only)
        int jc = j - 8192;
        int nT = jc >> 12, nt = (jc >> 10) & 3, ks = (jc >> 6) & 15, lane = jc & 63;
        int quad = lane >> 4, l16 = lane & 15;
        int col = nT * 64 + nt * 16 + l16, k0 = ks * 32 + quad * 8;
        bf16x8 h;
#pragma unroll
        for (int i = 0; i < 8; ++i)
            h[i] = (bf16_t)Wd[(k0 + i) * 512 + col];
        *(bf16x8*)(ws + OFF_WD + (size_t)jc * 8) = h;
    }
}

// ------------------- K0b: xprep (X -> fragment-major hi/lo bf16) ------------
__global__ __launch_bounds__(256) void xprep_kernel(const float* __restrict__ x,
                                                    bf16_t* __restrict__ ws) {
    int mt = blockIdx.x;
    int tid = threadIdx.x;
    const float* xb = x + (size_t)mt * 32768;
#pragma unroll
    for (int it = 0; it < 16; ++it) {
        int c = it * 256 + tid;                // 16B-pair chunk: 8 f32
        int row = c >> 6, col8 = c & 63;
        f32x4 a0 = *(const f32x4*)(xb + c * 8);
        f32x4 a1 = *(const f32x4*)(xb + c * 8 + 4);
        bf16x8 h, l;
#pragma unroll
        for (int jj = 0; jj < 4; ++jj) {
            bf16_t h0 = (bf16_t)a0[jj];
            bf16_t h1 = (bf16_t)a1[jj];
            h[jj] = h0;     l[jj] = (bf16_t)(a0[jj] - (float)h0);
            h[4 + jj] = h1; l[4 + jj] = (bf16_t)(a1[jj] - (float)h1);
        }
        int w = row >> 4, l16 = row & 15, ks = col8 >> 2, quad = col8 & 3;
        size_t dst = (size_t)mt * 32768 + w * 8192 + ks * 512 + (quad * 16 + l16) * 8;
        *(bf16x8*)(ws + OFF_XHF + dst) = h;
        *(bf16x8*)(ws + OFF_XLF + dst) = l;
    }
}

// --------------------------- K1: fused QKV projection -----------------------
// grid (256, 6): blockIdx.x = 64-row stripe, blockIdx.y = output group.
// All operand loads are fragment-major: base + lane*16B, fully coalesced.
__global__ __launch_bounds__(256, 1) void qkv_kernel(bf16_t* __restrict__ ws) {
    int mt = blockIdx.x;                       // 0..255
    int g  = blockIdx.y;                       // 0..5
    int tid = threadIdx.x;
    int w = tid >> 6, lane = tid & 63, quad = lane >> 4, l16 = lane & 15;

    __shared__ __align__(16) bf16_t Vs[64][72];

    size_t xoff = (size_t)mt * 32768 + w * 8192 + lane * 8;

    if (g < 2) {
        bf16x8 xh[16], xl[16];
#pragma unroll
        for (int ks = 0; ks < 16; ++ks)
            xh[ks] = *(const bf16x8*)(ws + OFF_XHF + xoff + ks * 512);
#pragma unroll
        for (int ks = 0; ks < 16; ++ks)
            xl[ks] = *(const bf16x8*)(ws + OFF_XLF + xoff + ks * 512);

        const bf16_t* whf = ws + (g == 0 ? OFF_WBH : OFF_WCH) + lane * 8;
        const bf16_t* wlf = ws + (g == 0 ? OFF_WBL : OFF_WCL) + lane * 8;
        f32x4 acc[4];
#pragma unroll
        for (int nt = 0; nt < 4; ++nt) acc[nt] = (f32x4){0.f, 0.f, 0.f, 0.f};
#pragma unroll
        for (int ks = 0; ks < 16; ++ks) {
#pragma unroll
            for (int nt = 0; nt < 4; ++nt) {
                bf16x8 bh = *(const bf16x8*)(whf + (nt * 16 + ks) * 512);
                bf16x8 bl = *(const bf16x8*)(wlf + (nt * 16 + ks) * 512);
                acc[nt] = mfma16(xh[ks], bh, acc[nt]);
                acc[nt] = mfma16(xh[ks], bl, acc[nt]);
                acc[nt] = mfma16(xl[ks], bh, acc[nt]);
            }
        }
        unsigned base_h = (g == 0) ? OFF_QH : OFF_KH;
        unsigned base_l = (g == 0) ? OFF_QL : OFF_KL;
#pragma unroll
        for (int nt = 0; nt < 4; ++nt) {
            int gc = nt * 16 + l16;
#pragma unroll
            for (int r = 0; r < 4; ++r) {
                int gr = mt * 64 + w * 16 + quad * 4 + r;
                int b = gr >> 12, np = gr & 4095;
                float v = acc[nt][r];
                bf16_t h = (bf16_t)v;
                size_t o = ((size_t)(b * 4096 + np)) * 64 + gc;
                ws[base_h + o] = h;
                ws[base_l + o] = (bf16_t)(v - (float)h);
            }
        }
    } else {
        bf16x8 xh[16];
#pragma unroll
        for (int ks = 0; ks < 16; ++ks)
            xh[ks] = *(const bf16x8*)(ws + OFF_XHF + xoff + ks * 512);

        for (int t = 0; t < 2; ++t) {
            int nT = (g - 2) * 2 + t;
            const bf16_t* wdf = ws + OFF_WD + lane * 8;
            f32x4 acc[4];
#pragma unroll
            for (int nt = 0; nt < 4; ++nt) acc[nt] = (f32x4){0.f, 0.f, 0.f, 0.f};
#pragma unroll
            for (int ks = 0; ks < 16; ++ks) {
#pragma unroll
                for (int nt = 0; nt < 4; ++nt) {
                    bf16x8 bb = *(const bf16x8*)(wdf + (size_t)(((nT * 4 + nt) * 16 + ks)) * 512);
                    acc[nt] = mfma16(xh[ks], bb, acc[nt]);
                }
            }
#pragma unroll
            for (int nt = 0; nt < 4; ++nt) {
                bf16_t pk[4];
#pragma unroll
                for (int r = 0; r < 4; ++r) pk[r] = (bf16_t)acc[nt][r];
                *(u64*)&Vs[nt * 16 + l16][w * 16 + quad * 4] = *(u64*)pk;
            }
            __syncthreads();
            int gr0 = mt * 64;
            int bb = gr0 >> 12, np0 = gr0 & 4095;
            int ch = tid >> 2, seg = tid & 3;
            f32x4 d0 = *(const f32x4*)&Vs[ch][seg * 16];
            f32x4 d1 = *(const f32x4*)&Vs[ch][seg * 16 + 8];
            bf16_t* dst = ws + OFF_VT +
                ((size_t)bb * 512 + (size_t)(nT * 64 + ch)) * VSTRIDE + np0 + seg * 16;
            *(f32x4*)(dst) = d0;
            *(f32x4*)(dst + 8) = d1;
            __syncthreads();
        }
    }
}

// --------------------------- K2: scores + exp -------------------------------
// T1 XCD chunking (m204 bijective, 4096%8==0): dispatch id i -> original id
// (i&7)*512 + (i>>3). Each XCD processes 512 consecutive originals = 16
// complete (b,nt) groups -> Q-tile + whole K[b] (~2MB hi+lo) stay in that
// XCD's L2 instead of being re-fetched from L3 per block.
__global__ __launch_bounds__(256, 2) void score_kernel(bf16_t* __restrict__ ws) {
    int i = blockIdx.x;
    int idx = (i & 7) * 512 + (i >> 3);        // bijective over 4096
    int mt = idx & 31;
    int nt = (idx >> 5) & 31;
    int b  = idx >> 10;
    int tid = threadIdx.x;
    int w = tid >> 6, lane = tid & 63, quad = lane >> 4, l16 = lane & 15;
    int wr = w >> 1, wc = w & 1;

    __shared__ __align__(16) bf16_t Ls[128][136];

    const bf16_t* Qh = ws + OFF_QH + (size_t)b * NN * 64;
    const bf16_t* Ql = ws + OFF_QL + (size_t)b * NN * 64;
    const bf16_t* Kh = ws + OFF_KH + (size_t)b * NN * 64;
    const bf16_t* Kl = ws + OFF_KL + (size_t)b * NN * 64;

    bf16x8 qh[4][2], ql[4][2];
#pragma unroll
    for (int rt = 0; rt < 4; ++rt) {
        size_t qo = (size_t)(nt * 128 + wr * 64 + rt * 16 + l16) * 64 + quad * 8;
        qh[rt][0] = *(const bf16x8*)(Qh + qo);
        qh[rt][1] = *(const bf16x8*)(Qh + qo + 32);
        ql[rt][0] = *(const bf16x8*)(Ql + qo);
        ql[rt][1] = *(const bf16x8*)(Ql + qo + 32);
    }

    f32x4 s[4][4];
#pragma unroll
    for (int ct = 0; ct < 4; ++ct) {
        size_t ko = (size_t)(mt * 128 + wc * 64 + ct * 16 + l16) * 64 + quad * 8;
        bf16x8 kh0 = *(const bf16x8*)(Kh + ko);
        bf16x8 kh1 = *(const bf16x8*)(Kh + ko + 32);
        bf16x8 kl0 = *(const bf16x8*)(Kl + ko);
        bf16x8 kl1 = *(const bf16x8*)(Kl + ko + 32);
#pragma unroll
        for (int rt = 0; rt < 4; ++rt) {
            f32x4 a = (f32x4){0.f, 0.f, 0.f, 0.f};
            a = mfma16(qh[rt][0], kh0, a);
            a = mfma16(qh[rt][1], kh1, a);
            a = mfma16(qh[rt][0], kl0, a);
            a = mfma16(qh[rt][1], kl1, a);
            a = mfma16(ql[rt][0], kh0, a);
            a = mfma16(ql[rt][1], kh1, a);
            s[rt][ct] = a;
        }
    }

#pragma unroll
    for (int rt = 0; rt < 4; ++rt)
#pragma unroll
        for (int ct = 0; ct < 4; ++ct)
#pragma unroll
            for (int r = 0; r < 4; ++r) {
                float p = __expf(s[rt][ct][r] - ESHIFT);
                Ls[wr * 64 + rt * 16 + quad * 4 + r][wc * 64 + ct * 16 + l16] = (bf16_t)p;
            }
    __syncthreads();

    bf16_t* P = ws + OFF_P + (size_t)b * PBATCH;
    int row0 = tid >> 4, chunk = tid & 15;
#pragma unroll
    for (int it = 0; it < 8; ++it) {
        int row = it * 16 + row0;
        f32x4 d = *(const f32x4*)&Ls[row][chunk * 8];
        *(f32x4*)(P + (size_t)(nt * 128 + row) * PSTRIDE + mt * 128 + chunk * 8) = d;
    }
}

// --------------------------- K3: O = P V + epilogue -------------------------
// EXACT R18 body (83.4us proven). Block = XCD-swizzled (b, nt, ct4): 128x128
// output, K=4096 in 64 steps of 64. Double-buffered LDS [128][64] x2 (64 KB,
// 2 blocks/CU). Per step:
//   s_barrier; stage(t+1); vmcnt(8); s_barrier; sched_barrier; compute(t).
// vmcnt(8): FIFO holds t's 8 + (t+1)'s 8 -> retires exactly tile t; tile
// t+1 crosses barrier in flight (no drain). Loop unrolled x2 -> static
// buffer indices (rule #20). XOR chunk swizzle (tid&7)^(row&7) both-sides
// (measured 0 conflicts). osum static.
__global__ __launch_bounds__(256, 2) void pv_kernel(const float* __restrict__ x,
                                                    const float* __restrict__ gamma_p,
                                                    const bf16_t* __restrict__ ws,
                                                    float* __restrict__ out) {
    int i = blockIdx.x;
    // XCD swizzle: siblings {ct4=0..3 of one (b,nt)} share i&7 -> same XCD.
    int xcd = i & 7, r = i >> 3;
    int ct4 = r & 3, gu = r >> 2;
    int g = gu * 8 + xcd;                      // 0..127
    int b = g & 3, nt = g >> 2;                // nt 0..31
    int tid = threadIdx.x;
    int w = tid >> 6, lane = tid & 63, quad = lane >> 4, l16 = lane & 15;
    int wr = w >> 1, wc = w & 1;

    __shared__ __align__(16) bf16_t Pt[2][8192];   // [128 rows][64 m] swizzled
    __shared__ __align__(16) bf16_t Vt[2][8192];   // [128 ch][64 m] swizzled

    const bf16_t* P = ws + OFF_P + (size_t)b * PBATCH + (size_t)(nt * 128) * PSTRIDE;
    const bf16_t* V = ws + OFF_VT + (size_t)b * CC * VSTRIDE + (size_t)(ct4 * 128) * VSTRIDE;

    int sr = tid >> 3;
    int sc = (tid & 7) ^ (sr & 7);
    const bf16_t* gp = P + (size_t)sr * PSTRIDE + sc * 8;
    const bf16_t* gv = V + (size_t)sr * VSTRIDE + sc * 8;

    f32x4 o[4][4];
#pragma unroll
    for (int rt = 0; rt < 4; ++rt)
#pragma unroll
        for (int ct = 0; ct < 4; ++ct) o[rt][ct] = (f32x4){0.f, 0.f, 0.f, 0.f};
    f32x4 osum[4];
#pragma unroll
    for (int rt = 0; rt < 4; ++rt) osum[rt] = (f32x4){0.f, 0.f, 0.f, 0.f};

    bf16_t onev = (bf16_t)1.0f;
    bf16x8 vones = {onev, onev, onev, onev, onev, onev, onev, onev};

    auto stage = [&](int buf, int t) {
        int m0 = t * 64;
        load_lds16(gp + m0,                  &Pt[buf][tid * 8]);
        load_lds16(gp + 32u * PSTRIDE + m0,  &Pt[buf][2048 + tid * 8]);
        load_lds16(gp + 64u * PSTRIDE + m0,  &Pt[buf][4096 + tid * 8]);
        load_lds16(gp + 96u * PSTRIDE + m0,  &Pt[buf][6144 + tid * 8]);
        load_lds16(gv + m0,                  &Vt[buf][tid * 8]);
        load_lds16(gv + 32u * VSTRIDE + m0,  &Vt[buf][2048 + tid * 8]);
        load_lds16(gv + 64u * VSTRIDE + m0,  &Vt[buf][4096 + tid * 8]);
        load_lds16(gv + 96u * VSTRIDE + m0,  &Vt[buf][6144 + tid * 8]);
    };

    auto compute = [&](int buf) {
#pragma unroll
        for (int kk = 0; kk < 2; ++kk) {
            bf16x8 pa[4], vb[4];
#pragma unroll
            for (int rt = 0; rt < 4; ++rt) {
                int R = wr * 64 + rt * 16 + l16;
                int mc = (kk * 4 + quad) ^ (R & 7);
                pa[rt] = *(const bf16x8*)&Pt[buf][R * 64 + mc * 8];
            }
#pragma unroll
            for (int ct = 0; ct < 4; ++ct) {
                int Rv = wc * 64 + ct * 16 + l16;
                int mc = (kk * 4 + quad) ^ (Rv & 7);
                vb[ct] = *(const bf16x8*)&Vt[buf][Rv * 64 + mc * 8];
            }
#pragma unroll
            for (int ct = 0; ct < 4; ++ct)
#pragma unroll
                for (int rt = 0; rt < 4; ++rt)
                    o[rt][ct] = mfma16(pa[rt], vb[ct], o[rt][ct]);
            if (wc == 0) {
                osum[0] = mfma16(pa[0], vones, osum[0]);
                osum[1] = mfma16(pa[1], vones, osum[1]);
                osum[2] = mfma16(pa[2], vones, osum[2]);
                osum[3] = mfma16(pa[3], vones, osum[3]);
            }
        }
    };

#define PV_STEP(bufA, bufB, tnext)                            \
    __builtin_amdgcn_s_barrier();                             \
    stage(bufB, tnext);                                       \
    asm volatile("s_waitcnt vmcnt(8)" ::: "memory");          \
    __builtin_amdgcn_s_barrier();                             \
    __builtin_amdgcn_sched_barrier(0);                        \
    compute(bufA);

    stage(0, 0);
    for (int tt = 0; tt < 62; tt += 2) {
        PV_STEP(0, 1, tt + 1)                  // compute t=tt   (buf0)
        PV_STEP(1, 0, tt + 2)                  // compute t=tt+1 (buf1)
    }
    // t = 62 (buf0), stage t=63 into buf1
    PV_STEP(0, 1, 63)
    // t = 63 (buf1), nothing left to stage
    __builtin_amdgcn_s_barrier();
    asm volatile("s_waitcnt vmcnt(0)" ::: "memory");
    __builtin_amdgcn_s_barrier();
    __builtin_amdgcn_sched_barrier(0);
    compute(1);
#undef PV_STEP

    // rsum via LDS: Pt[0] is dead (last read at t=62; compute(1) reads Pt[1]).
    float* rsum_s = (float*)&Pt[0][0];
    if (wc == 0 && l16 == 0) {
#pragma unroll
        for (int rt = 0; rt < 4; ++rt)
#pragma unroll
            for (int rr = 0; rr < 4; ++rr)
                rsum_s[wr * 64 + rt * 16 + quad * 4 + rr] = osum[rt][rr];
    }
    __syncthreads();

    float gmm = gamma_p[0];
#pragma unroll
    for (int rt = 0; rt < 4; ++rt) {
        f32x4 rs = *(const f32x4*)&rsum_s[wr * 64 + rt * 16 + quad * 4];
        f32x4 linv;
#pragma unroll
        for (int rr = 0; rr < 4; ++rr) linv[rr] = 1.0f / rs[rr];
#pragma unroll
        for (int ct = 0; ct < 4; ++ct) {
#pragma unroll
            for (int rr = 0; rr < 4; ++rr) {
                int n = nt * 128 + wr * 64 + rt * 16 + quad * 4 + rr;
                int c = ct4 * 128 + wc * 64 + ct * 16 + l16;
                size_t off = ((size_t)(b * 4096 + n)) * 512 + c;
                out[off] = gmm * (o[rt][ct][rr] * linv[rr]) + x[off];
            }
        }
    }
}

// ---------------------------------------------------------------------------
extern "C" void kernel_launch(void* const* d_in, const int* in_sizes, int n_in,
                              void* d_out, int out_size, void* d_ws, size_t ws_size,
                              hipStream_t stream) {
    const float* x     = (const float*)d_in[0];
    const float* Wb    = (const float*)d_in[1];
    const float* Wc    = (const float*)d_in[2];
    const float* Wd    = (const float*)d_in[3];
    const float* gamma = (const float*)d_in[4];
    bf16_t* ws = (bf16_t*)d_ws;
    float* out = (float*)d_out;

    prep_kernel<<<160, 256, 0, stream>>>(Wb, Wc, Wd, ws);
    xprep_kernel<<<256, 256, 0, stream>>>(x, ws);
    qkv_kernel<<<dim3(256, 6), 256, 0, stream>>>(ws);
    score_kernel<<<4096, 256, 0, stream>>>(ws);
    pv_kernel<<<512, 256, 0, stream>>>(x, gamma, ws, out);
}